// Round 9
// baseline (454.863 us; speedup 1.0000x reference)
//
#include <hip/hip_runtime.h>
#include <stdint.h>

typedef __bf16 bf16_t;
typedef bf16_t bf16x8 __attribute__((ext_vector_type(8)));
typedef bf16_t bf16x4 __attribute__((ext_vector_type(4)));
typedef bf16_t bf16x2 __attribute__((ext_vector_type(2)));
typedef float  f32x4  __attribute__((ext_vector_type(4)));

typedef __attribute__((address_space(3))) void* as3p;
typedef const __attribute__((address_space(1))) void* as1p;

#define IN_C 512
#define HID  256
#define OUTC 128

__device__ inline bf16x8 cvt8(float4 a, float4 b) {
  bf16x8 o;
  o[0] = (bf16_t)a.x; o[1] = (bf16_t)a.y; o[2] = (bf16_t)a.z; o[3] = (bf16_t)a.w;
  o[4] = (bf16_t)b.x; o[5] = (bf16_t)b.y; o[6] = (bf16_t)b.z; o[7] = (bf16_t)b.w;
  return o;
}

// ---------------- fused prep: weight transposes + cnt zero + format detect ----
__global__ void k_prep(const float* __restrict__ W1, const float* __restrict__ W2,
                       const void* __restrict__ ei, int* __restrict__ flag,
                       int* __restrict__ cnt, bf16_t* __restrict__ W1t,
                       bf16_t* __restrict__ W2t, int n) {
  int u = blockIdx.x * blockDim.x + threadIdx.x;
  if (u < IN_C * HID) {
    W1t[(size_t)(u & 255) * IN_C + (u >> 8)] = (bf16_t)W1[u];
    return;
  }
  u -= IN_C * HID;
  if (u < HID * OUTC) {
    W2t[(size_t)(u & 127) * HID + (u >> 7)] = (bf16_t)W2[u];
    return;
  }
  u -= HID * OUTC;
  if (u < n) {
    cnt[u] = 0;
    return;
  }
  if (u == n) {
    const long long* p = (const long long*)ei;
    int ok = 1;
    for (int i = 0; i < 64; ++i) {
      long long v = p[i];
      if (v < 0 || v >= n) ok = 0;
    }
    *flag = ok;  // 1 => int64 layout, 0 => int32 layout
  }
}

__global__ void k_hist(const void* __restrict__ ei, const int* __restrict__ flag,
                       int* __restrict__ cnt, int E) {
  int e = blockIdx.x * blockDim.x + threadIdx.x;
  if (e >= E) return;
  int d;
  if (*flag) d = (int)((const long long*)ei)[(size_t)E + e];
  else       d = ((const int*)ei)[E + e];
  atomicAdd(&cnt[d], 1);
}

// ---------------- fused scan: per-block base recompute + local scan + dinv ----
__global__ void k_scan(const int* __restrict__ cnt, int* __restrict__ rs,
                       int* __restrict__ cur, float* __restrict__ dinv,
                       int n, int Etot) {
  __shared__ int sh[256];
  const int b = blockIdx.x, t = threadIdx.x;
  // base = sum cnt[0 .. b*256)   (b*256 <= n always)
  int p = 0;
  for (int j = t; j < b * 256; j += 256) p += cnt[j];
  sh[t] = p;
  __syncthreads();
  for (int off = 128; off > 0; off >>= 1) {
    if (t < off) sh[t] += sh[t + off];
    __syncthreads();
  }
  int base = sh[0];
  __syncthreads();
  // local inclusive scan of this block's 256 cnt values
  int i = b * 256 + t;
  int v = (i < n) ? cnt[i] : 0;
  if (i < n) dinv[i] = rsqrtf((float)v + 1.0f);  // +1 self-loop
  sh[t] = v;
  __syncthreads();
  int val = v;
  for (int off = 1; off < 256; off <<= 1) {
    int tt = (t >= off) ? sh[t - off] : 0;
    __syncthreads();
    val += tt;
    sh[t] = val;
    __syncthreads();
  }
  if (i < n) {
    int r = base + val - v;  // exclusive
    rs[i] = r;
    cur[i] = r;
  }
  if (i == 0) rs[n] = Etot;
}

// CSR fill (4B entries; dinv looked up at aggregation time)
__global__ void k_fill(const void* __restrict__ ei, const int* __restrict__ flag,
                       int* __restrict__ cur, int* __restrict__ csr, int E) {
  int e = blockIdx.x * blockDim.x + threadIdx.x;
  if (e >= E) return;
  int s, d;
  if (*flag) {
    const long long* p = (const long long*)ei;
    s = (int)p[e];
    d = (int)p[(size_t)E + e];
  } else {
    const int* p = (const int*)ei;
    s = p[e];
    d = p[E + e];
  }
  int pos = atomicAdd(&cur[d], 1);
  csr[pos] = s;
}

// ---------------- GEMM1: H1b[mpad,256] = bf16( x[fp32] @ W1 ) -----------------
// BM=128, BN=256 (full width, x read once). R2-proven staging: global->VGPR
// (fp32->bf16 cvt) -> padded LDS. 4 waves 2x2, wave tile 64x128, 32 MFMA/barrier.
__global__ __launch_bounds__(256, 2) void k_gemm1(const float* __restrict__ x,
                                                  const bf16_t* __restrict__ W1t,
                                                  bf16_t* __restrict__ C, int n) {
  __shared__ bf16_t As[128 * 40];
  __shared__ bf16_t Bs[256 * 40];
  const int bm = blockIdx.x;
  const int tid = threadIdx.x;
  const int wave = tid >> 6, lane = tid & 63;
  const int wm = (wave >> 1) * 64, wn = (wave & 1) * 128;
  const int quad = lane >> 4, l16 = lane & 15;
  const int arow = tid >> 1, acol = (tid & 1) * 16;  // 2 threads/row, 16 fp32 each
  const int grow = bm * 128 + arow;
  const bool av = grow < n;
  const float* ap = x + (size_t)grow * IN_C + acol;
  const bf16_t* bp = W1t + (size_t)tid * IN_C;  // thread = output col

  f32x4 acc[4][8];
#pragma unroll
  for (int i = 0; i < 4; ++i)
#pragma unroll
    for (int j = 0; j < 8; ++j)
#pragma unroll
      for (int r = 0; r < 4; ++r) acc[i][j][r] = 0.0f;

  for (int kk = 0; kk < IN_C; kk += 32) {
    float4 z = {0, 0, 0, 0};
    float4 a0 = av ? *(const float4*)(ap + kk)      : z;
    float4 a1 = av ? *(const float4*)(ap + kk + 4)  : z;
    float4 a2 = av ? *(const float4*)(ap + kk + 8)  : z;
    float4 a3 = av ? *(const float4*)(ap + kk + 12) : z;
    bf16x8 vb0 = *(const bf16x8*)(bp + kk);
    bf16x8 vb1 = *(const bf16x8*)(bp + kk + 8);
    bf16x8 vb2 = *(const bf16x8*)(bp + kk + 16);
    bf16x8 vb3 = *(const bf16x8*)(bp + kk + 24);
    bf16x8 va0 = cvt8(a0, a1);
    bf16x8 va1 = cvt8(a2, a3);
    __syncthreads();  // previous iteration's fragment reads complete
    *(bf16x8*)(&As[arow * 40 + acol]) = va0;
    *(bf16x8*)(&As[arow * 40 + acol + 8]) = va1;
    *(bf16x8*)(&Bs[tid * 40]) = vb0;
    *(bf16x8*)(&Bs[tid * 40 + 8]) = vb1;
    *(bf16x8*)(&Bs[tid * 40 + 16]) = vb2;
    *(bf16x8*)(&Bs[tid * 40 + 24]) = vb3;
    __syncthreads();
    bf16x8 af[4], bf[8];
#pragma unroll
    for (int i = 0; i < 4; ++i)
      af[i] = *(const bf16x8*)(&As[(wm + i * 16 + l16) * 40 + quad * 8]);
#pragma unroll
    for (int j = 0; j < 8; ++j)
      bf[j] = *(const bf16x8*)(&Bs[(wn + j * 16 + l16) * 40 + quad * 8]);
#pragma unroll
    for (int i = 0; i < 4; ++i)
#pragma unroll
      for (int j = 0; j < 8; ++j)
        acc[i][j] = __builtin_amdgcn_mfma_f32_16x16x32_bf16(af[i], bf[j], acc[i][j], 0, 0, 0);
  }

#pragma unroll
  for (int i = 0; i < 4; ++i) {
#pragma unroll
    for (int j = 0; j < 8; ++j) {
      int col = wn + j * 16 + l16;
      int row0 = bm * 128 + wm + i * 16 + quad * 4;
#pragma unroll
      for (int r = 0; r < 4; ++r)
        C[(size_t)(row0 + r) * HID + col] = (bf16_t)acc[i][j][r];
    }
  }
}

// ---------------- GEMM2 (m97 structure, unchanged from R8): bf16 out ----------
__global__ __launch_bounds__(256, 3) void k_gemm2(const bf16_t* __restrict__ A,
                                                  const bf16_t* __restrict__ Bt,
                                                  bf16_t* __restrict__ C) {
  __shared__ bf16_t As[128 * 32];
  __shared__ bf16_t Bs[128 * 32];
  const int bm = blockIdx.x;
  const int tid = threadIdx.x;
  const int wave = tid >> 6, lane = tid & 63;
  const int wm = (wave >> 1) * 64, wn = (wave & 1) * 64;
  const int quad = lane >> 4, l16 = lane & 15;
  const size_t abase = (size_t)bm * 128 * HID;

  f32x4 acc[4][4];
#pragma unroll
  for (int i = 0; i < 4; ++i)
#pragma unroll
    for (int j = 0; j < 4; ++j)
#pragma unroll
      for (int r = 0; r < 4; ++r) acc[i][j][r] = 0.0f;

  for (int kk = 0; kk < HID; kk += 32) {
#pragma unroll
    for (int i = 0; i < 2; ++i) {
      int g = i * 256 + tid;
      int row = g >> 2, col = (g & 3) * 8;
      const bf16_t* ga = A + abase + (size_t)row * HID + kk + col;
      __builtin_amdgcn_global_load_lds((as1p)ga,
                                       (as3p)(&As[(i * 256 + wave * 64) * 8]), 16, 0, 0);
      const bf16_t* gb = Bt + (size_t)row * HID + kk + col;
      __builtin_amdgcn_global_load_lds((as1p)gb,
                                       (as3p)(&Bs[(i * 256 + wave * 64) * 8]), 16, 0, 0);
    }
    __syncthreads();
    bf16x8 af[4], bf[4];
#pragma unroll
    for (int i = 0; i < 4; ++i)
      af[i] = *(const bf16x8*)(&As[(wm + i * 16 + l16) * 32 + quad * 8]);
#pragma unroll
    for (int j = 0; j < 4; ++j)
      bf[j] = *(const bf16x8*)(&Bs[(wn + j * 16 + l16) * 32 + quad * 8]);
#pragma unroll
    for (int i = 0; i < 4; ++i)
#pragma unroll
      for (int j = 0; j < 4; ++j)
        acc[i][j] = __builtin_amdgcn_mfma_f32_16x16x32_bf16(af[i], bf[j], acc[i][j], 0, 0, 0);
    __syncthreads();
  }

#pragma unroll
  for (int i = 0; i < 4; ++i) {
#pragma unroll
    for (int j = 0; j < 4; ++j) {
      int col = wn + j * 16 + l16;
      int row0 = bm * 128 + wm + i * 16 + quad * 4;
#pragma unroll
      for (int r = 0; r < 4; ++r)
        C[(size_t)(row0 + r) * OUTC + col] = (bf16_t)acc[i][j][r];
    }
  }
}

// ---------------- layer-1 aggregation (bf16 gather, 8 in flight) ----------
__global__ void k_agg_l1(const bf16_t* __restrict__ H, const int* __restrict__ rs,
                         const int* __restrict__ csr, const float* __restrict__ dinv,
                         const float* __restrict__ b1, bf16_t* __restrict__ R,
                         int n, int mpad) {
  int d = blockIdx.x * 4 + (threadIdx.x >> 6);
  if (d >= mpad) return;
  int lane = threadIdx.x & 63;
  if (d >= n) {
    bf16x4 z;
    z[0] = (bf16_t)0.0f; z[1] = (bf16_t)0.0f; z[2] = (bf16_t)0.0f; z[3] = (bf16_t)0.0f;
    *(bf16x4*)(R + (size_t)d * HID + lane * 4) = z;
    return;
  }
  int e0 = rs[d], e1 = rs[d + 1];
  float acc[4][4];
  for (int k = 0; k < 4; ++k)
    for (int c = 0; c < 4; ++c) acc[k][c] = 0.f;
  int e = e0;
  for (; e + 8 <= e1; e += 8) {
    int s[8];
    float w[8];
    bf16x4 h[8];
#pragma unroll
    for (int u = 0; u < 8; ++u) s[u] = csr[e + u];
#pragma unroll
    for (int u = 0; u < 8; ++u) w[u] = dinv[s[u]];
#pragma unroll
    for (int u = 0; u < 8; ++u)
      h[u] = *(const bf16x4*)(H + (size_t)s[u] * HID + lane * 4);
#pragma unroll
    for (int u = 0; u < 8; ++u)
#pragma unroll
      for (int c = 0; c < 4; ++c) acc[u & 3][c] += w[u] * (float)h[u][c];
  }
  for (; e < e1; ++e) {
    int sx = csr[e];
    float wx = dinv[sx];
    bf16x4 hx = *(const bf16x4*)(H + (size_t)sx * HID + lane * 4);
#pragma unroll
    for (int c = 0; c < 4; ++c) acc[0][c] += wx * (float)hx[c];
  }
  float dd = dinv[d];
  float dv2 = dd * dd;
  bf16x4 hs = *(const bf16x4*)(H + (size_t)d * HID + lane * 4);
  float4 bb = ((const float4*)b1)[lane];
  float a0 = (acc[0][0] + acc[1][0]) + (acc[2][0] + acc[3][0]);
  float a1 = (acc[0][1] + acc[1][1]) + (acc[2][1] + acc[3][1]);
  float a2 = (acc[0][2] + acc[1][2]) + (acc[2][2] + acc[3][2]);
  float a3 = (acc[0][3] + acc[1][3]) + (acc[2][3] + acc[3][3]);
  float v0 = fmaxf(a0 * dd + dv2 * (float)hs[0] + bb.x, 0.f);
  float v1 = fmaxf(a1 * dd + dv2 * (float)hs[1] + bb.y, 0.f);
  float v2 = fmaxf(a2 * dd + dv2 * (float)hs[2] + bb.z, 0.f);
  float v3 = fmaxf(a3 * dd + dv2 * (float)hs[3] + bb.w, 0.f);
  bf16x4 o;
  o[0] = (bf16_t)v0; o[1] = (bf16_t)v1; o[2] = (bf16_t)v2; o[3] = (bf16_t)v3;
  *(bf16x4*)(R + (size_t)d * HID + lane * 4) = o;
}

// ---------------- layer-2 aggregation (bf16 gather, 8 in flight) ----------
__global__ void k_agg_l2(const bf16_t* __restrict__ H, const int* __restrict__ rs,
                         const int* __restrict__ csr, const float* __restrict__ dinv,
                         const float* __restrict__ b2, float* __restrict__ out, int n) {
  int d = blockIdx.x * 4 + (threadIdx.x >> 6);
  if (d >= n) return;
  int lane = threadIdx.x & 63;
  int e0 = rs[d], e1 = rs[d + 1];
  float acc[4][2];
  for (int k = 0; k < 4; ++k) { acc[k][0] = 0.f; acc[k][1] = 0.f; }
  int e = e0;
  for (; e + 8 <= e1; e += 8) {
    int s[8];
    float w[8];
    bf16x2 h[8];
#pragma unroll
    for (int u = 0; u < 8; ++u) s[u] = csr[e + u];
#pragma unroll
    for (int u = 0; u < 8; ++u) w[u] = dinv[s[u]];
#pragma unroll
    for (int u = 0; u < 8; ++u)
      h[u] = *(const bf16x2*)(H + (size_t)s[u] * OUTC + lane * 2);
#pragma unroll
    for (int u = 0; u < 8; ++u) {
      acc[u & 3][0] += w[u] * (float)h[u][0];
      acc[u & 3][1] += w[u] * (float)h[u][1];
    }
  }
  for (; e < e1; ++e) {
    int sx = csr[e];
    float wx = dinv[sx];
    bf16x2 hx = *(const bf16x2*)(H + (size_t)sx * OUTC + lane * 2);
    acc[0][0] += wx * (float)hx[0];
    acc[0][1] += wx * (float)hx[1];
  }
  float a0 = (acc[0][0] + acc[1][0]) + (acc[2][0] + acc[3][0]);
  float a1 = (acc[0][1] + acc[1][1]) + (acc[2][1] + acc[3][1]);
  float dd = dinv[d];
  float dv2 = dd * dd;
  bf16x2 hs = *(const bf16x2*)(H + (size_t)d * OUTC + lane * 2);
  float2 bb = ((const float2*)b2)[lane];
  float2 o;
  o.x = a0 * dd + dv2 * (float)hs[0] + bb.x;
  o.y = a1 * dd + dv2 * (float)hs[1] + bb.y;
  ((float2*)(out + (size_t)d * OUTC))[lane] = o;
}

// ---------------- launch ----------------
extern "C" void kernel_launch(void* const* d_in, const int* in_sizes, int n_in,
                              void* d_out, int out_size, void* d_ws, size_t ws_size,
                              hipStream_t stream) {
  const float* x  = (const float*)d_in[0];
  const void*  ei = d_in[1];
  const float* W1 = (const float*)d_in[2];
  const float* b1 = (const float*)d_in[3];
  const float* W2 = (const float*)d_in[4];
  const float* b2 = (const float*)d_in[5];

  const int n = in_sizes[0] / IN_C;    // 50000
  const int E = in_sizes[1] / 2;       // 800000
  const int mpad = (n + 127) & ~127;   // 50048

  char* w = (char*)d_ws;
  size_t off = 0;
  auto alloc = [&](size_t bytes) -> void* {
    void* p = w + off;
    off = (off + bytes + 255) & ~(size_t)255;
    return p;
  };

  int*    flag = (int*)alloc(4);
  int*    cnt  = (int*)alloc((size_t)n * 4);
  float*  dinv = (float*)alloc((size_t)n * 4);
  int*    rs   = (int*)alloc((size_t)(n + 1) * 4);
  int*    cur  = (int*)alloc((size_t)n * 4);
  int*    csr  = (int*)alloc((size_t)E * 4);
  bf16_t* W1t  = (bf16_t*)alloc((size_t)HID * IN_C * 2);
  bf16_t* W2t  = (bf16_t*)alloc((size_t)OUTC * HID * 2);
  bf16_t* H1b  = (bf16_t*)alloc((size_t)mpad * HID * 2);
  bf16_t* R1b  = (bf16_t*)alloc((size_t)mpad * HID * 2);
  bf16_t* H2b  = (bf16_t*)alloc((size_t)mpad * OUTC * 2);
  (void)ws_size; (void)n_in; (void)out_size;

  const int nb = (n + 255) / 256;
  const int prepT = IN_C * HID + HID * OUTC + n + 1;

  k_prep<<<(prepT + 255) / 256, 256, 0, stream>>>(W1, W2, ei, flag, cnt, W1t, W2t, n);
  k_hist<<<(E + 255) / 256, 256, 0, stream>>>(ei, flag, cnt, E);
  k_scan<<<nb, 256, 0, stream>>>(cnt, rs, cur, dinv, n, E);
  k_fill<<<(E + 255) / 256, 256, 0, stream>>>(ei, flag, cur, csr, E);

  k_gemm1<<<mpad / 128, 256, 0, stream>>>(x, W1t, H1b, n);
  k_agg_l1<<<(mpad + 3) / 4, 256, 0, stream>>>(H1b, rs, csr, dinv, b1, R1b, n, mpad);
  k_gemm2<<<mpad / 128, 256, 0, stream>>>(R1b, W2t, H2b);
  k_agg_l2<<<(n + 3) / 4, 256, 0, stream>>>(H2b, rs, csr, dinv, b2, (float*)d_out, n);
}

// Round 10
// 426.574 us; speedup vs baseline: 1.0663x; 1.0663x over previous
//
#include <hip/hip_runtime.h>
#include <stdint.h>

typedef __bf16 bf16_t;
typedef bf16_t bf16x8 __attribute__((ext_vector_type(8)));
typedef bf16_t bf16x4 __attribute__((ext_vector_type(4)));
typedef bf16_t bf16x2 __attribute__((ext_vector_type(2)));
typedef float  f32x4  __attribute__((ext_vector_type(4)));

typedef __attribute__((address_space(3))) void* as3p;
typedef const __attribute__((address_space(1))) void* as1p;

#define IN_C 512
#define HID  256
#define OUTC 128

// ---------------- fused prep: convx + weight transposes + cnt zero + detect ----
__global__ void k_prep(const float* __restrict__ x, const float* __restrict__ W1,
                       const float* __restrict__ W2, const void* __restrict__ ei,
                       int* __restrict__ flag, int* __restrict__ cnt,
                       bf16_t* __restrict__ Xb, bf16_t* __restrict__ W1t,
                       bf16_t* __restrict__ W2t, int n, int mpad) {
  int t = blockIdx.x * blockDim.x + threadIdx.x;
  const int NC = mpad * 64;
  if (t < NC) {
    int r = t >> 6, c8 = t & 63;
    bf16x8 o;
    if (r < n) {
      const float4* px = (const float4*)(x + (size_t)r * IN_C);
      float4 a = px[c8 * 2];
      float4 b = px[c8 * 2 + 1];
      o[0] = (bf16_t)a.x; o[1] = (bf16_t)a.y; o[2] = (bf16_t)a.z; o[3] = (bf16_t)a.w;
      o[4] = (bf16_t)b.x; o[5] = (bf16_t)b.y; o[6] = (bf16_t)b.z; o[7] = (bf16_t)b.w;
    } else {
      for (int i = 0; i < 8; ++i) o[i] = (bf16_t)0.0f;
    }
    *(bf16x8*)(Xb + (size_t)r * IN_C + c8 * 8) = o;
    return;
  }
  int u = t - NC;
  if (u < IN_C * HID) {
    W1t[(size_t)(u & 255) * IN_C + (u >> 8)] = (bf16_t)W1[u];
    return;
  }
  u -= IN_C * HID;
  if (u < HID * OUTC) {
    W2t[(size_t)(u & 127) * HID + (u >> 7)] = (bf16_t)W2[u];
    return;
  }
  u -= HID * OUTC;
  if (u < n) {
    cnt[u] = 0;
    return;
  }
  if (u == n) {
    const long long* p = (const long long*)ei;
    int ok = 1;
    for (int i = 0; i < 64; ++i) {
      long long v = p[i];
      if (v < 0 || v >= n) ok = 0;
    }
    *flag = ok;  // 1 => int64 layout, 0 => int32 layout
  }
}

__global__ void k_hist(const void* __restrict__ ei, const int* __restrict__ flag,
                       int* __restrict__ cnt, int E) {
  int e = blockIdx.x * blockDim.x + threadIdx.x;
  if (e >= E) return;
  int d;
  if (*flag) d = (int)((const long long*)ei)[(size_t)E + e];
  else       d = ((const int*)ei)[E + e];
  atomicAdd(&cnt[d], 1);
}

// ---------------- fused scan: per-block base recompute + local scan + dinv ----
__global__ void k_scan(const int* __restrict__ cnt, int* __restrict__ rs,
                       int* __restrict__ cur, float* __restrict__ dinv,
                       int n, int Etot) {
  __shared__ int sh[256];
  const int b = blockIdx.x, t = threadIdx.x;
  int p = 0;
  for (int j = t; j < b * 256; j += 256) p += cnt[j];
  sh[t] = p;
  __syncthreads();
  for (int off = 128; off > 0; off >>= 1) {
    if (t < off) sh[t] += sh[t + off];
    __syncthreads();
  }
  int base = sh[0];
  __syncthreads();
  int i = b * 256 + t;
  int v = (i < n) ? cnt[i] : 0;
  if (i < n) dinv[i] = rsqrtf((float)v + 1.0f);  // +1 self-loop
  sh[t] = v;
  __syncthreads();
  int val = v;
  for (int off = 1; off < 256; off <<= 1) {
    int tt = (t >= off) ? sh[t - off] : 0;
    __syncthreads();
    val += tt;
    sh[t] = val;
    __syncthreads();
  }
  if (i < n) {
    int r = base + val - v;  // exclusive
    rs[i] = r;
    cur[i] = r;
  }
  if (i == 0) rs[n] = Etot;
}

// CSR fill (4B entries; dinv looked up at aggregation time)
__global__ void k_fill(const void* __restrict__ ei, const int* __restrict__ flag,
                       int* __restrict__ cur, int* __restrict__ csr, int E) {
  int e = blockIdx.x * blockDim.x + threadIdx.x;
  if (e >= E) return;
  int s, d;
  if (*flag) {
    const long long* p = (const long long*)ei;
    s = (int)p[e];
    d = (int)p[(size_t)E + e];
  } else {
    const int* p = (const int*)ei;
    s = p[e];
    d = p[E + e];
  }
  int pos = atomicAdd(&cur[d], 1);
  csr[pos] = s;
}

// ---------------- bf16 MFMA GEMM (m97 structure, R8-proven): C = A * Bt^T -----
// BM=BN=128, BK=32, 256 threads / 4 waves (2x2 of 64x64).
// Staging via global_load_lds width=16 into unpadded lane-ordered [128][32] tiles.
__global__ __launch_bounds__(256, 3) void k_gemm(const bf16_t* __restrict__ A,
                                                 const bf16_t* __restrict__ Bt,
                                                 bf16_t* __restrict__ C,
                                                 int Kdim, int Ncols) {
  __shared__ bf16_t As[128 * 32];
  __shared__ bf16_t Bs[128 * 32];
  const int bm = blockIdx.x, bn = blockIdx.y;
  const int tid = threadIdx.x;
  const int wave = tid >> 6, lane = tid & 63;
  const int wm = (wave >> 1) * 64, wn = (wave & 1) * 64;
  const int quad = lane >> 4, l16 = lane & 15;

  const size_t abase = (size_t)bm * 128 * Kdim;
  const size_t bbase = (size_t)bn * 128 * Kdim;

  f32x4 acc[4][4];
#pragma unroll
  for (int i = 0; i < 4; ++i)
#pragma unroll
    for (int j = 0; j < 4; ++j)
#pragma unroll
      for (int r = 0; r < 4; ++r) acc[i][j][r] = 0.0f;

  for (int kk = 0; kk < Kdim; kk += 32) {
#pragma unroll
    for (int i = 0; i < 2; ++i) {
      int g = i * 256 + tid;
      int row = g >> 2, col = (g & 3) * 8;
      const bf16_t* ga = A + abase + (size_t)row * Kdim + kk + col;
      __builtin_amdgcn_global_load_lds((as1p)ga,
                                       (as3p)(&As[(i * 256 + wave * 64) * 8]), 16, 0, 0);
      const bf16_t* gb = Bt + bbase + (size_t)row * Kdim + kk + col;
      __builtin_amdgcn_global_load_lds((as1p)gb,
                                       (as3p)(&Bs[(i * 256 + wave * 64) * 8]), 16, 0, 0);
    }
    __syncthreads();
    bf16x8 af[4], bf[4];
#pragma unroll
    for (int i = 0; i < 4; ++i)
      af[i] = *(const bf16x8*)(&As[(wm + i * 16 + l16) * 32 + quad * 8]);
#pragma unroll
    for (int j = 0; j < 4; ++j)
      bf[j] = *(const bf16x8*)(&Bs[(wn + j * 16 + l16) * 32 + quad * 8]);
#pragma unroll
    for (int i = 0; i < 4; ++i)
#pragma unroll
      for (int j = 0; j < 4; ++j)
        acc[i][j] = __builtin_amdgcn_mfma_f32_16x16x32_bf16(af[i], bf[j], acc[i][j], 0, 0, 0);
    __syncthreads();
  }

#pragma unroll
  for (int i = 0; i < 4; ++i) {
#pragma unroll
    for (int j = 0; j < 4; ++j) {
      int col = bn * 128 + wn + j * 16 + l16;
      int row0 = bm * 128 + wm + i * 16 + quad * 4;
#pragma unroll
      for (int r = 0; r < 4; ++r)
        C[(size_t)(row0 + r) * Ncols + col] = (bf16_t)acc[i][j][r];
    }
  }
}

// ---------------- layer-1 aggregation (bf16 gather, 8 in flight) ----------
__global__ void k_agg_l1(const bf16_t* __restrict__ H, const int* __restrict__ rs,
                         const int* __restrict__ csr, const float* __restrict__ dinv,
                         const float* __restrict__ b1, bf16_t* __restrict__ R,
                         int n, int mpad) {
  int d = blockIdx.x * 4 + (threadIdx.x >> 6);
  if (d >= mpad) return;
  int lane = threadIdx.x & 63;
  if (d >= n) {
    bf16x4 z;
    z[0] = (bf16_t)0.0f; z[1] = (bf16_t)0.0f; z[2] = (bf16_t)0.0f; z[3] = (bf16_t)0.0f;
    *(bf16x4*)(R + (size_t)d * HID + lane * 4) = z;
    return;
  }
  int e0 = rs[d], e1 = rs[d + 1];
  float acc[4][4];
  for (int k = 0; k < 4; ++k)
    for (int c = 0; c < 4; ++c) acc[k][c] = 0.f;
  int e = e0;
  for (; e + 8 <= e1; e += 8) {
    int s[8];
    float w[8];
    bf16x4 h[8];
#pragma unroll
    for (int u = 0; u < 8; ++u) s[u] = csr[e + u];
#pragma unroll
    for (int u = 0; u < 8; ++u) w[u] = dinv[s[u]];
#pragma unroll
    for (int u = 0; u < 8; ++u)
      h[u] = *(const bf16x4*)(H + (size_t)s[u] * HID + lane * 4);
#pragma unroll
    for (int u = 0; u < 8; ++u)
#pragma unroll
      for (int c = 0; c < 4; ++c) acc[u & 3][c] += w[u] * (float)h[u][c];
  }
  for (; e < e1; ++e) {
    int sx = csr[e];
    float wx = dinv[sx];
    bf16x4 hx = *(const bf16x4*)(H + (size_t)sx * HID + lane * 4);
#pragma unroll
    for (int c = 0; c < 4; ++c) acc[0][c] += wx * (float)hx[c];
  }
  float dd = dinv[d];
  float dv2 = dd * dd;
  bf16x4 hs = *(const bf16x4*)(H + (size_t)d * HID + lane * 4);
  float4 bb = ((const float4*)b1)[lane];
  float a0 = (acc[0][0] + acc[1][0]) + (acc[2][0] + acc[3][0]);
  float a1 = (acc[0][1] + acc[1][1]) + (acc[2][1] + acc[3][1]);
  float a2 = (acc[0][2] + acc[1][2]) + (acc[2][2] + acc[3][2]);
  float a3 = (acc[0][3] + acc[1][3]) + (acc[2][3] + acc[3][3]);
  float v0 = fmaxf(a0 * dd + dv2 * (float)hs[0] + bb.x, 0.f);
  float v1 = fmaxf(a1 * dd + dv2 * (float)hs[1] + bb.y, 0.f);
  float v2 = fmaxf(a2 * dd + dv2 * (float)hs[2] + bb.z, 0.f);
  float v3 = fmaxf(a3 * dd + dv2 * (float)hs[3] + bb.w, 0.f);
  bf16x4 o;
  o[0] = (bf16_t)v0; o[1] = (bf16_t)v1; o[2] = (bf16_t)v2; o[3] = (bf16_t)v3;
  *(bf16x4*)(R + (size_t)d * HID + lane * 4) = o;
}

// ---------------- layer-2 aggregation (bf16 gather, 8 in flight) ----------
__global__ void k_agg_l2(const bf16_t* __restrict__ H, const int* __restrict__ rs,
                         const int* __restrict__ csr, const float* __restrict__ dinv,
                         const float* __restrict__ b2, float* __restrict__ out, int n) {
  int d = blockIdx.x * 4 + (threadIdx.x >> 6);
  if (d >= n) return;
  int lane = threadIdx.x & 63;
  int e0 = rs[d], e1 = rs[d + 1];
  float acc[4][2];
  for (int k = 0; k < 4; ++k) { acc[k][0] = 0.f; acc[k][1] = 0.f; }
  int e = e0;
  for (; e + 8 <= e1; e += 8) {
    int s[8];
    float w[8];
    bf16x2 h[8];
#pragma unroll
    for (int u = 0; u < 8; ++u) s[u] = csr[e + u];
#pragma unroll
    for (int u = 0; u < 8; ++u) w[u] = dinv[s[u]];
#pragma unroll
    for (int u = 0; u < 8; ++u)
      h[u] = *(const bf16x2*)(H + (size_t)s[u] * OUTC + lane * 2);
#pragma unroll
    for (int u = 0; u < 8; ++u) {
      acc[u & 3][0] += w[u] * (float)h[u][0];
      acc[u & 3][1] += w[u] * (float)h[u][1];
    }
  }
  for (; e < e1; ++e) {
    int sx = csr[e];
    float wx = dinv[sx];
    bf16x2 hx = *(const bf16x2*)(H + (size_t)sx * OUTC + lane * 2);
    acc[0][0] += wx * (float)hx[0];
    acc[0][1] += wx * (float)hx[1];
  }
  float a0 = (acc[0][0] + acc[1][0]) + (acc[2][0] + acc[3][0]);
  float a1 = (acc[0][1] + acc[1][1]) + (acc[2][1] + acc[3][1]);
  float dd = dinv[d];
  float dv2 = dd * dd;
  bf16x2 hs = *(const bf16x2*)(H + (size_t)d * OUTC + lane * 2);
  float2 bb = ((const float2*)b2)[lane];
  float2 o;
  o.x = a0 * dd + dv2 * (float)hs[0] + bb.x;
  o.y = a1 * dd + dv2 * (float)hs[1] + bb.y;
  ((float2*)(out + (size_t)d * OUTC))[lane] = o;
}

// ---------------- launch ----------------
extern "C" void kernel_launch(void* const* d_in, const int* in_sizes, int n_in,
                              void* d_out, int out_size, void* d_ws, size_t ws_size,
                              hipStream_t stream) {
  const float* x  = (const float*)d_in[0];
  const void*  ei = d_in[1];
  const float* W1 = (const float*)d_in[2];
  const float* b1 = (const float*)d_in[3];
  const float* W2 = (const float*)d_in[4];
  const float* b2 = (const float*)d_in[5];

  const int n = in_sizes[0] / IN_C;    // 50000
  const int E = in_sizes[1] / 2;       // 800000
  const int mpad = (n + 127) & ~127;   // 50048

  char* w = (char*)d_ws;
  size_t off = 0;
  auto alloc = [&](size_t bytes) -> void* {
    void* p = w + off;
    off = (off + bytes + 255) & ~(size_t)255;
    return p;
  };

  int*    flag = (int*)alloc(4);
  int*    cnt  = (int*)alloc((size_t)n * 4);
  float*  dinv = (float*)alloc((size_t)n * 4);
  int*    rs   = (int*)alloc((size_t)(n + 1) * 4);
  int*    cur  = (int*)alloc((size_t)n * 4);
  int*    csr  = (int*)alloc((size_t)E * 4);
  bf16_t* Xb   = (bf16_t*)alloc((size_t)mpad * IN_C * 2);
  bf16_t* W1t  = (bf16_t*)alloc((size_t)HID * IN_C * 2);
  bf16_t* W2t  = (bf16_t*)alloc((size_t)OUTC * HID * 2);
  bf16_t* H1b  = (bf16_t*)alloc((size_t)mpad * HID * 2);
  bf16_t* R1b  = (bf16_t*)alloc((size_t)mpad * HID * 2);
  bf16_t* H2b  = (bf16_t*)alloc((size_t)mpad * OUTC * 2);
  (void)ws_size; (void)n_in; (void)out_size;

  const int nb = (n + 255) / 256;
  const int prepT = mpad * 64 + IN_C * HID + HID * OUTC + n + 1;

  k_prep<<<(prepT + 255) / 256, 256, 0, stream>>>(x, W1, W2, ei, flag, cnt,
                                                  Xb, W1t, W2t, n, mpad);
  k_hist<<<(E + 255) / 256, 256, 0, stream>>>(ei, flag, cnt, E);
  k_scan<<<nb, 256, 0, stream>>>(cnt, rs, cur, dinv, n, E);
  k_fill<<<(E + 255) / 256, 256, 0, stream>>>(ei, flag, cur, csr, E);

  k_gemm<<<dim3(mpad / 128, HID / 128), 256, 0, stream>>>(Xb, W1t, H1b, IN_C, HID);
  k_agg_l1<<<(mpad + 3) / 4, 256, 0, stream>>>(H1b, rs, csr, dinv, b1, R1b, n, mpad);
  k_gemm<<<dim3(mpad / 128, OUTC / 128), 256, 0, stream>>>(R1b, W2t, H2b, HID, OUTC);
  k_agg_l2<<<(n + 3) / 4, 256, 0, stream>>>(H2b, rs, csr, dinv, b2, (float*)d_out, n);
}